// Round 1
// baseline (111.149 us; speedup 1.0000x reference)
//
#include <hip/hip_runtime.h>

// DTFormer: B=64, L=1024, S=8, D=128
// Key insight chain:
//  1. match counts via per-batch histogram over packed (id,snap) keys (16000 keys)
//  2. _agg_mlp is symmetric in channel axis -> dst [::-1] flip is a no-op
//  3. out[b,l,:] depends only on (c0, c1, sn) -> tabulate Phi[sn][c0][c1][128]
//     for c < 16 (counts are Poisson(0.064), never reach 16), slow path otherwise.
// Final pass = table gather + 64MB coalesced write -> HBM-write roofline (~10us).

#define LSEQ 1024
#define NBATCH 64
#define DDIM 128
#define NKEYS 16384
#define CMAX 16

// ---------------- Kernel 1: per-batch histogram + count extraction ----------
__global__ __launch_bounds__(1024) void count_kernel(
    const int* __restrict__ src_ids, const int* __restrict__ dst_ids,
    const int* __restrict__ src_sn,  const int* __restrict__ dst_sn,
    unsigned int* __restrict__ cnt_src, unsigned int* __restrict__ cnt_dst)
{
    __shared__ unsigned int hist[NKEYS];   // src count in lo16, dst count in hi16
    const int b = blockIdx.x;
    const int t = threadIdx.x;

    for (int i = t; i < NKEYS; i += 1024) hist[i] = 0u;
    __syncthreads();

    const int base = b * LSEQ;
    const int sid = src_ids[base + t];
    const int ssn = src_sn[base + t];
    const int did = dst_ids[base + t];
    const int dsn = dst_sn[base + t];

    unsigned int skey = (unsigned int)(sid * 8 + ((ssn - 1) & 7));
    unsigned int dkey = (unsigned int)(did * 8 + ((dsn - 1) & 7));
    if (skey >= NKEYS) skey = NKEYS - 1;   // safety clamp (never hit: id<2000)
    if (dkey >= NKEYS) dkey = NKEYS - 1;

    atomicAdd(&hist[skey], 1u);
    atomicAdd(&hist[dkey], 65536u);
    __syncthreads();

    const unsigned int hs = hist[skey];
    const unsigned int hd = hist[dkey];
    const unsigned int s_self  = hs & 0xffffu, s_cross = hs >> 16;
    const unsigned int d_self  = hd >> 16,     d_cross = hd & 0xffffu;
    const unsigned int sv = (sid != 0) ? 1u : 0u;
    const unsigned int dv = (did != 0) ? 1u : 0u;

    // pack: c0 | c1<<11 | sn<<22   (counts <= 1024 fit in 11 bits)
    cnt_src[base + t] = (s_self * sv) | ((s_cross * sv) << 11)
                        | ((unsigned int)((ssn - 1) & 7) << 22);
    cnt_dst[base + t] = (d_self * dv) | ((d_cross * dv) << 11)
                        | ((unsigned int)((dsn - 1) & 7) << 22);
}

// ---------------- Kernel 2: build Phi table [8][16][16][128] ----------------
__global__ __launch_bounds__(128) void table_kernel(
    const float* __restrict__ agg_w1, const float* __restrict__ agg_b1,
    const float* __restrict__ agg_w2, const float* __restrict__ agg_b2,
    const float* __restrict__ enc_w1, const float* __restrict__ enc_b1,
    const float* __restrict__ enc_w2, const float* __restrict__ enc_b2,
    float* __restrict__ table)
{
    const int bx = blockIdx.x;          // [0, 8*16*16)
    const int sn = bx >> 8;
    const int c0 = (bx >> 4) & 15;
    const int c1 = bx & 15;
    const int d  = threadIdx.x;

    __shared__ float red0[DDIM], red1[DDIM], g[DDIM];

    // agg MLP layer 1+2 partials (y_e = b2[e] + 0.5*(psi_e(c0)+psi_e(c1)))
    const float w1d = agg_w1[sn * DDIM + d];
    const float b1d = agg_b1[d];
    const float h = fmaxf((float)c0 * w1d + b1d, 0.0f)
                  + fmaxf((float)c1 * w1d + b1d, 0.0f);
    red0[d] = h * agg_w2[d * 2 + 0];
    red1[d] = h * agg_w2[d * 2 + 1];
    __syncthreads();
    for (int s = 64; s > 0; s >>= 1) {
        if (d < s) { red0[d] += red0[d + s]; red1[d] += red1[d + s]; }
        __syncthreads();
    }
    const float y0 = agg_b2[0] + 0.5f * red0[0];
    const float y1 = agg_b2[1] + 0.5f * red1[0];
    __syncthreads();

    // encoder: g[k] = relu(y0*w1e+b1e) + relu(y1*w1e+b1e)
    const float w1e = enc_w1[d], b1e = enc_b1[d];
    g[d] = fmaxf(y0 * w1e + b1e, 0.0f) + fmaxf(y1 * w1e + b1e, 0.0f);
    __syncthreads();

    float acc = 2.0f * enc_b2[d];
    #pragma unroll 8
    for (int k = 0; k < DDIM; ++k)
        acc += g[k] * enc_w2[k * DDIM + d];
    table[bx * DDIM + d] = acc;
}

// ---------------- Kernel 3: gather + write (HBM-roofline pass) --------------
__global__ __launch_bounds__(256) void gather_kernel(
    const unsigned int* __restrict__ cnt_src,
    const unsigned int* __restrict__ cnt_dst,
    const float* __restrict__ table,
    const float* __restrict__ agg_w1, const float* __restrict__ agg_b1,
    const float* __restrict__ agg_w2, const float* __restrict__ agg_b2,
    const float* __restrict__ enc_w1, const float* __restrict__ enc_b1,
    const float* __restrict__ enc_w2, const float* __restrict__ enc_b2,
    float* __restrict__ out)
{
    const int gt   = blockIdx.x * 256 + threadIdx.x;  // one float4 per thread
    const int unit = gt >> 5;                          // (side, b, l)
    const int q    = gt & 31;                          // float4 index within D
    const int side = unit >> 16;                       // 65536 units per side
    const int idx  = unit & 65535;

    const unsigned int packed = side ? cnt_dst[idx] : cnt_src[idx];
    const unsigned int c0 = packed & 0x7FFu;
    const unsigned int c1 = (packed >> 11) & 0x7FFu;
    const unsigned int sn = (packed >> 22) & 7u;

    float4 v;
    if (c0 < CMAX && c1 < CMAX) {
        const float4* src = (const float4*)(table
            + ((sn * 256u + c0 * 16u + c1) * DDIM));
        v = src[q];
    } else {
        // exact slow path (counts >= 16: effectively never on this input)
        float s0 = 0.0f, s1 = 0.0f;
        for (int dd = 0; dd < DDIM; ++dd) {
            const float w1d = agg_w1[sn * DDIM + dd];
            const float b1d = agg_b1[dd];
            const float h = fmaxf((float)c0 * w1d + b1d, 0.0f)
                          + fmaxf((float)c1 * w1d + b1d, 0.0f);
            s0 += h * agg_w2[dd * 2 + 0];
            s1 += h * agg_w2[dd * 2 + 1];
        }
        const float y0 = agg_b2[0] + 0.5f * s0;
        const float y1 = agg_b2[1] + 0.5f * s1;
        float o0 = 2.0f * enc_b2[q * 4 + 0];
        float o1 = 2.0f * enc_b2[q * 4 + 1];
        float o2 = 2.0f * enc_b2[q * 4 + 2];
        float o3 = 2.0f * enc_b2[q * 4 + 3];
        for (int k = 0; k < DDIM; ++k) {
            const float w1e = enc_w1[k], b1e = enc_b1[k];
            const float gk = fmaxf(y0 * w1e + b1e, 0.0f)
                           + fmaxf(y1 * w1e + b1e, 0.0f);
            o0 += gk * enc_w2[k * DDIM + q * 4 + 0];
            o1 += gk * enc_w2[k * DDIM + q * 4 + 1];
            o2 += gk * enc_w2[k * DDIM + q * 4 + 2];
            o3 += gk * enc_w2[k * DDIM + q * 4 + 3];
        }
        v = make_float4(o0, o1, o2, o3);
    }
    ((float4*)out)[gt] = v;
}

extern "C" void kernel_launch(void* const* d_in, const int* in_sizes, int n_in,
                              void* d_out, int out_size, void* d_ws, size_t ws_size,
                              hipStream_t stream)
{
    const int* src_ids = (const int*)d_in[0];
    const int* dst_ids = (const int*)d_in[1];
    const int* src_sn  = (const int*)d_in[2];
    const int* dst_sn  = (const int*)d_in[3];
    // d_in[4] = num_snapshots (hardcoded 8)
    const float* agg_w1 = (const float*)d_in[5];
    const float* agg_b1 = (const float*)d_in[6];
    const float* agg_w2 = (const float*)d_in[7];
    const float* agg_b2 = (const float*)d_in[8];
    const float* enc_w1 = (const float*)d_in[9];
    const float* enc_b1 = (const float*)d_in[10];
    const float* enc_w2 = (const float*)d_in[11];
    const float* enc_b2 = (const float*)d_in[12];
    float* out = (float*)d_out;

    // ws layout: cnt_src[65536] u32 | cnt_dst[65536] u32 | table[2048*128] f32
    unsigned int* cnt_src = (unsigned int*)d_ws;
    unsigned int* cnt_dst = cnt_src + NBATCH * LSEQ;
    float* table = (float*)(cnt_dst + NBATCH * LSEQ);

    count_kernel<<<NBATCH, 1024, 0, stream>>>(src_ids, dst_ids, src_sn, dst_sn,
                                              cnt_src, cnt_dst);
    table_kernel<<<8 * CMAX * CMAX, 128, 0, stream>>>(
        agg_w1, agg_b1, agg_w2, agg_b2, enc_w1, enc_b1, enc_w2, enc_b2, table);
    gather_kernel<<<(2 * NBATCH * LSEQ * 32) / 256, 256, 0, stream>>>(
        cnt_src, cnt_dst, table,
        agg_w1, agg_b1, agg_w2, agg_b2, enc_w1, enc_b1, enc_w2, enc_b2, out);
}